// Round 10
// baseline (2303.896 us; speedup 1.0000x reference)
//
#include <hip/hip_runtime.h>
#include <hip/hip_cooperative_groups.h>

namespace cg = cooperative_groups;

#define EPS 1e-8f
#define FSCALE 32768.0f              // 2^15 fixed-point scale per field
#define INV_FSCALE (1.0f / 32768.0f)
#define CHUNK 1024                   // vertices per WG in decode (12 KB LDS)
#define MAX_COOP_WGS 2048            // 8 WG/CU (12KB LDS, <=64 VGPR) * 256 CU

// ---------------- K1: face normals -> ONE packed u64 atomic per corner ----
// acc[v] (u64) accumulates  x*2^42 + y*2^21 + z  (each field: signed fixed
// point, scale 2^15).  Mod-2^64 addition keeps every field's true sum exact;
// the decode below unwinds cross-field borrows exactly.
__global__ void __launch_bounds__(256)
k1_face_atomics(const float* __restrict__ verts,
                const int* __restrict__ idx,
                unsigned long long* __restrict__ acc,
                int M) {
    int f = blockIdx.x * blockDim.x + threadIdx.x;
    if (f >= M) return;

    int i0 = idx[3 * f + 0];
    int i1 = idx[3 * f + 1];
    int i2 = idx[3 * f + 2];

    float v0x = verts[3 * i0 + 0], v0y = verts[3 * i0 + 1], v0z = verts[3 * i0 + 2];
    float v1x = verts[3 * i1 + 0], v1y = verts[3 * i1 + 1], v1z = verts[3 * i1 + 2];
    float v2x = verts[3 * i2 + 0], v2y = verts[3 * i2 + 1], v2z = verts[3 * i2 + 2];

    float e1x = v1x - v0x, e1y = v1y - v0y, e1z = v1z - v0z;
    float e2x = v2x - v0x, e2y = v2y - v0y, e2z = v2z - v0z;

    float cx = e1y * e2z - e1z * e2y;
    float cy = e1z * e2x - e1x * e2z;
    float cz = e1x * e2y - e1y * e2x;

    float n = sqrtf(cx * cx + cy * cy + cz * cz);
    float inv = 1.0f / fmaxf(n, EPS);

    long long xs = (long long)__float2int_rn(cx * inv * FSCALE);
    long long ys = (long long)__float2int_rn(cy * inv * FSCALE);
    long long zs = (long long)__float2int_rn(cz * inv * FSCALE);

    unsigned long long pk = ((unsigned long long)xs << 42)
                          + ((unsigned long long)ys << 21)
                          +  (unsigned long long)zs;

    atomicAdd(&acc[i0], pk);
    atomicAdd(&acc[i1], pk);
    atomicAdd(&acc[i2], pk);
}

// ---------------- K2 (cooperative): decode + normalize + in-place repack --
// acc overlaps out (bytes [0,16MB) of d_out). Decode everything this WG owns
// into LDS, grid.sync (ALL reads done grid-wide), then write final floats.
__global__ void __launch_bounds__(256)
k2_decode_normalize(unsigned long long* __restrict__ acc,
                    float* __restrict__ out,
                    int N, int chunk) {
    cg::grid_group grid = cg::this_grid();
    __shared__ __align__(16) float lds[CHUNK * 3];

    int a = blockIdx.x * chunk;
    int b = min(a + chunk, N);

    for (int v = a + (int)threadIdx.x; v < b; v += 256) {
        unsigned long long T = acc[v];
        // exact 3-field decode (borrow-cancelling)
        long long C = ((long long)(T << 43)) >> 43;          // low 21 bits, sext
        unsigned long long T1 = T - (unsigned long long)C;
        long long B = ((long long)(T1 << 22)) >> 43;         // bits 21..41, sext
        unsigned long long T2 = T1 - ((unsigned long long)B << 21);
        long long A = ((long long)T2) >> 42;                 // top 22 bits, sext

        float x = (float)A * INV_FSCALE;
        float y = (float)B * INV_FSCALE;
        float z = (float)C * INV_FSCALE;
        float inv = 1.0f / fmaxf(sqrtf(x * x + y * y + z * z), EPS);
        int l = (v - a) * 3;
        lds[l + 0] = x * inv;
        lds[l + 1] = y * inv;
        lds[l + 2] = z * inv;
    }

    grid.sync();   // every acc[] read on the whole grid is complete

    int nF = (b - a) * 3;
    int gBase = a * 3;
    if ((nF & 3) == 0) {
        const float4* src = (const float4*)lds;
        float4* dst = (float4*)(out + gBase);   // gBase*4 = 12288*blk, 16B-aligned
        int n4 = nF >> 2;
        for (int i = threadIdx.x; i < n4; i += 256) dst[i] = src[i];
    } else {
        for (int i = threadIdx.x; i < nF; i += 256) out[gBase + i] = lds[i];
    }
}

// ---------------- fallback (rounds 1-2 proven) ----------------------------
__global__ void __launch_bounds__(256)
face_normals_kernel(const float* __restrict__ verts,
                    const int* __restrict__ idx,
                    float* __restrict__ acc,
                    int M) {
    int f = blockIdx.x * blockDim.x + threadIdx.x;
    if (f >= M) return;
    int i0 = idx[3 * f + 0], i1 = idx[3 * f + 1], i2 = idx[3 * f + 2];
    float v0x = verts[3 * i0], v0y = verts[3 * i0 + 1], v0z = verts[3 * i0 + 2];
    float v1x = verts[3 * i1], v1y = verts[3 * i1 + 1], v1z = verts[3 * i1 + 2];
    float v2x = verts[3 * i2], v2y = verts[3 * i2 + 1], v2z = verts[3 * i2 + 2];
    float e1x = v1x - v0x, e1y = v1y - v0y, e1z = v1z - v0z;
    float e2x = v2x - v0x, e2y = v2y - v0y, e2z = v2z - v0z;
    float cx = e1y * e2z - e1z * e2y;
    float cy = e1z * e2x - e1x * e2z;
    float cz = e1x * e2y - e1y * e2x;
    float n = sqrtf(cx * cx + cy * cy + cz * cz);
    float inv = 1.0f / fmaxf(n, EPS);
    cx *= inv; cy *= inv; cz *= inv;
    atomicAdd(&acc[3 * i0 + 0], cx); atomicAdd(&acc[3 * i0 + 1], cy); atomicAdd(&acc[3 * i0 + 2], cz);
    atomicAdd(&acc[3 * i1 + 0], cx); atomicAdd(&acc[3 * i1 + 1], cy); atomicAdd(&acc[3 * i1 + 2], cz);
    atomicAdd(&acc[3 * i2 + 0], cx); atomicAdd(&acc[3 * i2 + 1], cy); atomicAdd(&acc[3 * i2 + 2], cz);
}

__global__ void __launch_bounds__(256)
normalize_kernel(float* __restrict__ out, int N) {
    int v = blockIdx.x * blockDim.x + threadIdx.x;
    if (v >= N) return;
    float x = out[3 * v], y = out[3 * v + 1], z = out[3 * v + 2];
    float inv = 1.0f / fmaxf(sqrtf(x * x + y * y + z * z), EPS);
    out[3 * v] = x * inv; out[3 * v + 1] = y * inv; out[3 * v + 2] = z * inv;
}

extern "C" void kernel_launch(void* const* d_in, const int* in_sizes, int n_in,
                              void* d_out, int out_size, void* d_ws, size_t ws_size,
                              hipStream_t stream) {
    const float* verts = (const float*)d_in[0];
    const int* idx = (const int*)d_in[1];
    float* out = (float*)d_out;

    int N = in_sizes[0] / 3;   // 2,000,000 vertices
    int M = in_sizes[1] / 3;   // 4,000,000 faces

    const int BLOCK = 256;
    int gridA = (M + BLOCK - 1) / BLOCK;
    int gridB = (N + BLOCK - 1) / BLOCK;

    // packed accumulator: u64[N] at d_out bytes [0, 8N)  (8N <= 12N = out bytes)
    unsigned long long* acc = (unsigned long long*)d_out;
    int coopWGs = (N + CHUNK - 1) / CHUNK;   // 1954 for N=2M

    if (coopWGs <= MAX_COOP_WGS && ((size_t)out_size == (size_t)3 * N)) {
        hipMemsetAsync(d_out, 0, (size_t)N * sizeof(unsigned long long), stream);
        k1_face_atomics<<<gridA, BLOCK, 0, stream>>>(verts, idx, acc, M);

        int chunk = CHUNK;
        void* args[] = { &acc, &out, &N, &chunk };
        hipError_t err = hipLaunchCooperativeKernel((const void*)k2_decode_normalize,
                                                    dim3(coopWGs), dim3(256),
                                                    args, 0, stream);
        if (err == hipSuccess) return;
        // coop launch failed -> redo from scratch with the proven path
    }

    hipMemsetAsync(d_out, 0, (size_t)out_size * sizeof(float), stream);
    face_normals_kernel<<<gridA, BLOCK, 0, stream>>>(verts, idx, out, M);
    normalize_kernel<<<gridB, BLOCK, 0, stream>>>(out, N);
}

// Round 11
// 610.242 us; speedup vs baseline: 3.7754x; 3.7754x over previous
//
#include <hip/hip_runtime.h>
#include <hip/hip_cooperative_groups.h>

namespace cg = cooperative_groups;

#define EPS 1e-8f
#define FSCALE 32768.0f              // 2^15 fixed-point scale per field
#define INV_FSCALE (1.0f / 32768.0f)
#define CHUNK 2500                   // vertices per WG in decode (30 KB LDS)
#define DECODE_ITERS ((CHUNK + 255) / 256)   // 10
#define MAX_COOP_WGS 1280            // 800 WGs proven co-resident in round 9

// ---------------- K1: face normals -> ONE packed u64 atomic per corner ----
// acc[v] (u64) accumulates  x*2^42 + y*2^21 + z  (each field: signed fixed
// point, scale 2^15).  Mod-2^64 addition keeps every field's true sum exact;
// the decode below unwinds cross-field borrows exactly.
__global__ void __launch_bounds__(256)
k1_face_atomics(const float* __restrict__ verts,
                const int* __restrict__ idx,
                unsigned long long* __restrict__ acc,
                int M) {
    int f = blockIdx.x * blockDim.x + threadIdx.x;
    if (f >= M) return;

    int i0 = idx[3 * f + 0];
    int i1 = idx[3 * f + 1];
    int i2 = idx[3 * f + 2];

    float v0x = verts[3 * i0 + 0], v0y = verts[3 * i0 + 1], v0z = verts[3 * i0 + 2];
    float v1x = verts[3 * i1 + 0], v1y = verts[3 * i1 + 1], v1z = verts[3 * i1 + 2];
    float v2x = verts[3 * i2 + 0], v2y = verts[3 * i2 + 1], v2z = verts[3 * i2 + 2];

    float e1x = v1x - v0x, e1y = v1y - v0y, e1z = v1z - v0z;
    float e2x = v2x - v0x, e2y = v2y - v0y, e2z = v2z - v0z;

    float cx = e1y * e2z - e1z * e2y;
    float cy = e1z * e2x - e1x * e2z;
    float cz = e1x * e2y - e1y * e2x;

    float n = sqrtf(cx * cx + cy * cy + cz * cz);
    float inv = 1.0f / fmaxf(n, EPS);

    long long xs = (long long)__float2int_rn(cx * inv * FSCALE);
    long long ys = (long long)__float2int_rn(cy * inv * FSCALE);
    long long zs = (long long)__float2int_rn(cz * inv * FSCALE);

    unsigned long long pk = ((unsigned long long)xs << 42)
                          + ((unsigned long long)ys << 21)
                          +  (unsigned long long)zs;

    atomicAdd(&acc[i0], pk);
    atomicAdd(&acc[i1], pk);
    atomicAdd(&acc[i2], pk);
}

// ---------------- K2 (cooperative): decode + normalize + in-place repack --
// acc overlaps out (bytes [0,16MB) of d_out). Batch-load this WG's chunk of
// acc into registers (static unrolled indices -> stays in VGPRs, all loads
// in flight before one drain), decode+normalize into LDS, grid.sync (ALL
// acc reads grid-wide complete), then coalesced float4 writeback.
__global__ void __launch_bounds__(256)
k2_decode_normalize(unsigned long long* __restrict__ acc,
                    float* __restrict__ out,
                    int N, int chunk) {
    cg::grid_group grid = cg::this_grid();
    __shared__ __align__(16) float lds[CHUNK * 3];

    int a = blockIdx.x * chunk;
    int b = min(a + chunk, N);
    int tid = threadIdx.x;

    unsigned long long T[DECODE_ITERS];
#pragma unroll
    for (int i = 0; i < DECODE_ITERS; ++i) {
        int v = a + tid + i * 256;
        T[i] = (v < b) ? acc[v] : 0ULL;     // independent loads, one drain
    }

#pragma unroll
    for (int i = 0; i < DECODE_ITERS; ++i) {
        int v = a + tid + i * 256;
        if (v < b) {
            unsigned long long t = T[i];
            // exact 3-field decode (borrow-cancelling)
            long long C = ((long long)(t << 43)) >> 43;          // low 21, sext
            unsigned long long T1 = t - (unsigned long long)C;
            long long B = ((long long)(T1 << 22)) >> 43;         // bits 21..41
            unsigned long long T2 = T1 - ((unsigned long long)B << 21);
            long long A = ((long long)T2) >> 42;                 // top 22

            float x = (float)A * INV_FSCALE;
            float y = (float)B * INV_FSCALE;
            float z = (float)C * INV_FSCALE;
            float inv = 1.0f / fmaxf(sqrtf(x * x + y * y + z * z), EPS);
            int l = (v - a) * 3;
            lds[l + 0] = x * inv;
            lds[l + 1] = y * inv;
            lds[l + 2] = z * inv;
        }
    }

    grid.sync();   // every acc[] read on the whole grid is complete

    int nF = (b - a) * 3;
    int gBase = a * 3;
    if ((nF & 3) == 0) {
        const float4* src = (const float4*)lds;
        float4* dst = (float4*)(out + gBase);   // gBase*4 = 30000*blk, 16B-aligned
        int n4 = nF >> 2;
        for (int i = tid; i < n4; i += 256) dst[i] = src[i];
    } else {
        for (int i = tid; i < nF; i += 256) out[gBase + i] = lds[i];
    }
}

// ---------------- fallback (rounds 1-2 proven) ----------------------------
__global__ void __launch_bounds__(256)
face_normals_kernel(const float* __restrict__ verts,
                    const int* __restrict__ idx,
                    float* __restrict__ acc,
                    int M) {
    int f = blockIdx.x * blockDim.x + threadIdx.x;
    if (f >= M) return;
    int i0 = idx[3 * f + 0], i1 = idx[3 * f + 1], i2 = idx[3 * f + 2];
    float v0x = verts[3 * i0], v0y = verts[3 * i0 + 1], v0z = verts[3 * i0 + 2];
    float v1x = verts[3 * i1], v1y = verts[3 * i1 + 1], v1z = verts[3 * i1 + 2];
    float v2x = verts[3 * i2], v2y = verts[3 * i2 + 1], v2z = verts[3 * i2 + 2];
    float e1x = v1x - v0x, e1y = v1y - v0y, e1z = v1z - v0z;
    float e2x = v2x - v0x, e2y = v2y - v0y, e2z = v2z - v0z;
    float cx = e1y * e2z - e1z * e2y;
    float cy = e1z * e2x - e1x * e2z;
    float cz = e1x * e2y - e1y * e2x;
    float n = sqrtf(cx * cx + cy * cy + cz * cz);
    float inv = 1.0f / fmaxf(n, EPS);
    cx *= inv; cy *= inv; cz *= inv;
    atomicAdd(&acc[3 * i0 + 0], cx); atomicAdd(&acc[3 * i0 + 1], cy); atomicAdd(&acc[3 * i0 + 2], cz);
    atomicAdd(&acc[3 * i1 + 0], cx); atomicAdd(&acc[3 * i1 + 1], cy); atomicAdd(&acc[3 * i1 + 2], cz);
    atomicAdd(&acc[3 * i2 + 0], cx); atomicAdd(&acc[3 * i2 + 1], cy); atomicAdd(&acc[3 * i2 + 2], cz);
}

__global__ void __launch_bounds__(256)
normalize_kernel(float* __restrict__ out, int N) {
    int v = blockIdx.x * blockDim.x + threadIdx.x;
    if (v >= N) return;
    float x = out[3 * v], y = out[3 * v + 1], z = out[3 * v + 2];
    float inv = 1.0f / fmaxf(sqrtf(x * x + y * y + z * z), EPS);
    out[3 * v] = x * inv; out[3 * v + 1] = y * inv; out[3 * v + 2] = z * inv;
}

extern "C" void kernel_launch(void* const* d_in, const int* in_sizes, int n_in,
                              void* d_out, int out_size, void* d_ws, size_t ws_size,
                              hipStream_t stream) {
    const float* verts = (const float*)d_in[0];
    const int* idx = (const int*)d_in[1];
    float* out = (float*)d_out;

    int N = in_sizes[0] / 3;   // 2,000,000 vertices
    int M = in_sizes[1] / 3;   // 4,000,000 faces

    const int BLOCK = 256;
    int gridA = (M + BLOCK - 1) / BLOCK;
    int gridB = (N + BLOCK - 1) / BLOCK;

    // packed accumulator: u64[N] at d_out bytes [0, 8N)  (8N <= 12N = out bytes)
    unsigned long long* acc = (unsigned long long*)d_out;
    int coopWGs = (N + CHUNK - 1) / CHUNK;   // 800 for N=2M (proven co-resident)

    if (coopWGs <= MAX_COOP_WGS && ((size_t)out_size == (size_t)3 * N)) {
        hipMemsetAsync(d_out, 0, (size_t)N * sizeof(unsigned long long), stream);
        k1_face_atomics<<<gridA, BLOCK, 0, stream>>>(verts, idx, acc, M);

        int chunk = CHUNK;
        void* args[] = { &acc, &out, &N, &chunk };
        hipError_t err = hipLaunchCooperativeKernel((const void*)k2_decode_normalize,
                                                    dim3(coopWGs), dim3(256),
                                                    args, 0, stream);
        if (err == hipSuccess) return;
        // coop launch failed -> redo from scratch with the proven path
    }

    hipMemsetAsync(d_out, 0, (size_t)out_size * sizeof(float), stream);
    face_normals_kernel<<<gridA, BLOCK, 0, stream>>>(verts, idx, out, M);
    normalize_kernel<<<gridB, BLOCK, 0, stream>>>(out, N);
}